// Round 1
// 491.582 us; speedup vs baseline: 1.0091x; 1.0091x over previous
//
#include <hip/hip_runtime.h>
#include <stdint.h>

// Batched Viterbi decode: B=8192, T=512, K=12.
// NEW LAYOUT vs r0: 16 lanes per batch row, ONE output state per lane
// (lanes 0..11 live, 12..15 spare), 4 rows per 64-lane wave.
// => 2048 waves (2 per SIMD on all 1024 SIMDs) instead of 512 (0.5/SIMD):
// the per-step dependence chain is now hidden by a co-resident wave, and
// per-wave issue cost per step drops ~3x (1 column/lane instead of 3).
// Cross-lane gather of the 12 prev trellis values = 12 ds_swizzle group
// broadcasts (no LDS round-trip, no barrier). Emissions staged via the
// proven double-buffered global_load_lds schedule (32-step chunks).
// Backpointers: each lane packs its own nibble x8 steps into a dword,
// one fully-coalesced dword store per 8 steps; layout [B][64][16] dwords.
// Backtrack: 3x dwordx4 loads per 8-block (pipelined) + in-reg 12:1 mux.

namespace {

constexpr int kB = 8192;
constexpr int kT = 512;
constexpr int kK = 12;
constexpr int kRows = 4;     // batch rows per wave
constexpr int kRowF = 392;   // 384 staged floats + 8 pad: groups offset by 8
                             // banks => exactly 2 lanes/bank on em reads (free)

template <int I>
__device__ __forceinline__ float bcast16(float x) {
    // ds_swizzle BitMode: src_lane = ((l & 0x10) | I) within each 32-lane
    // half => broadcast lane I of each 16-lane group to the whole group.
    // offset = (xor<<10) | (or<<5) | and = (I<<5) | 0x10.
    return __int_as_float(__builtin_amdgcn_ds_swizzle(
        __float_as_int(x), (I << 5) | 0x10));
}

__global__ __launch_bounds__(64, 2) void viterbi_fused(
    const float* __restrict__ logits,   // [B, T, K]
    const float* __restrict__ trans,    // [K, K]
    float* __restrict__ out,            // [B] scores + [B*T] paths (floats)
    uint32_t* __restrict__ bp)          // [B][64][16] dwords, 8 nibbles each
{
    __shared__ float embuf[2][kRows][kRowF];   // 12544 B -> 8 blocks/CU easy

    const int ln    = threadIdx.x;      // 0..63
    const int grp   = ln >> 4;          // row within wave: 0..3
    const int jl    = ln & 15;          // state lane: 0..11 live, 12..15 spare
    const int j     = (jl < 12) ? jl : 11;   // clamp for transition loads
    const int brow0 = blockIdx.x * kRows;
    const int b     = brow0 + grp;

    // transition column j: T[i] = trans[i][j] (spare lanes duplicate col 11;
    // their results are never read: swizzles only source lanes 0..11)
    const float T0 = trans[0 * kK + j],  T1 = trans[1 * kK + j];
    const float T2 = trans[2 * kK + j],  T3 = trans[3 * kK + j];
    const float T4 = trans[4 * kK + j],  T5 = trans[5 * kK + j];
    const float T6 = trans[6 * kK + j],  T7 = trans[7 * kK + j];
    const float T8 = trans[8 * kK + j],  T9 = trans[9 * kK + j];
    const float T10 = trans[10 * kK + j], T11 = trans[11 * kK + j];

    uint32_t* __restrict__ bpq = bp + (size_t)b * 1024 + jl;

    // Async DMA of one 32-step chunk (384 floats/row) for the 4 rows.
    // LDS dest is wave-uniform base + lane*4; global src includes +ln.
#define DMA_CHUNK(cc) do {                                                    \
    const int dsel_ = (cc) & 1;                                               \
    _Pragma("unroll")                                                         \
    for (int r_ = 0; r_ < kRows; ++r_) {                                      \
        const float* gs_ = logits + (size_t)(brow0 + r_) * (kT * kK)          \
                           + (cc) * 384 + ln;                                 \
        float* ld_ = &embuf[dsel_][r_][0];                                    \
        _Pragma("unroll")                                                     \
        for (int p_ = 0; p_ < 6; ++p_) {                                      \
            __builtin_amdgcn_global_load_lds(                                 \
                (const __attribute__((address_space(1))) void*)(gs_ + p_ * 64),\
                (__attribute__((address_space(3))) void*)(ld_ + p_ * 64),     \
                4, 0, 0);                                                     \
        }                                                                     \
    }                                                                         \
} while (0)

    // staged emission read: this lane's state column at step t
    auto emrd = [&](int t) -> float {
        const int tc = (t < kT) ? t : (kT - 1);
        return embuf[(tc >> 5) & 1][grp][(tc & 31) * 12 + jl];
    };

    DMA_CHUNK(0);
    DMA_CHUNK(1);

    __builtin_amdgcn_wave_barrier();
    __builtin_amdgcn_s_waitcnt(0x0F70);   // vmcnt(0): chunks 0,1 landed
    __builtin_amdgcn_wave_barrier();

    // trellis t=0: nv = em[0][j]
    float nv = emrd(0);
    uint32_t acc = 0u;

    float e0 = emrd(1), e1 = emrd(2), e2 = emrd(3), e3 = emrd(4);
    float e4 = emrd(5), e5 = emrd(6), e6 = emrd(7), e7 = emrd(8);

    // One Viterbi step: 12 group-broadcasts, 12 adds, max3 tree, two-level
    // first-index argmax (groups of 3), nibble-pack into acc.
#define STEP(TT, EV) do {                                                     \
    const float p0 = bcast16<0>(nv),  p1 = bcast16<1>(nv);                    \
    const float p2 = bcast16<2>(nv),  p3 = bcast16<3>(nv);                    \
    const float p4 = bcast16<4>(nv),  p5 = bcast16<5>(nv);                    \
    const float p6 = bcast16<6>(nv),  p7 = bcast16<7>(nv);                    \
    const float p8 = bcast16<8>(nv),  p9 = bcast16<9>(nv);                    \
    const float p10 = bcast16<10>(nv), p11 = bcast16<11>(nv);                 \
    const float x0 = p0 + T0,  x1 = p1 + T1,  x2 = p2 + T2;                   \
    const float x3 = p3 + T3,  x4 = p4 + T4,  x5 = p5 + T5;                   \
    const float x6 = p6 + T6,  x7 = p7 + T7,  x8 = p8 + T8;                   \
    const float x9 = p9 + T9,  x10 = p10 + T10, x11 = p11 + T11;              \
    const float mA = fmaxf(fmaxf(x0, x1), x2);                                \
    const float mB = fmaxf(fmaxf(x3, x4), x5);                                \
    const float mC = fmaxf(fmaxf(x6, x7), x8);                                \
    const float mD = fmaxf(fmaxf(x9, x10), x11);                              \
    const float best = fmaxf(fmaxf(mA, mB), fmaxf(mC, mD));                   \
    int gA = (x1 == mA) ? 1 : 2;    gA = (x0 == mA) ? 0 : gA;                 \
    int gB = (x4 == mB) ? 4 : 5;    gB = (x3 == mB) ? 3 : gB;                 \
    int gC = (x7 == mC) ? 7 : 8;    gC = (x6 == mC) ? 6 : gC;                 \
    int gD = (x10 == mD) ? 10 : 11; gD = (x9 == mD) ? 9 : gD;                 \
    int bi = gD;                                                              \
    bi = (mC == best) ? gC : bi;                                              \
    bi = (mB == best) ? gB : bi;                                              \
    bi = (mA == best) ? gA : bi;                                              \
    nv = best + (EV);                                                         \
    acc |= (uint32_t)bi << (4 * (((TT) - 1) & 7));                            \
} while (0)

    // main: t = 1..504 in 63 sub-blocks of 8 (same DMA/wait schedule as r0)
#pragma unroll 1
    for (int sb = 0; sb < 63; ++sb) {
        const int tb = 8 * sb + 1;

        if ((sb & 3) == 2) {
            // next chunk's DMA (issued 3 sub-blocks ago) must have landed
            __builtin_amdgcn_wave_barrier();
            __builtin_amdgcn_s_waitcnt(0x0F70);   // vmcnt(0)
            __builtin_amdgcn_wave_barrier();
        }
        if ((sb & 3) == 3) {
            const int cc = (sb >> 2) + 2;
            if (cc <= 15) {
                // drain ds_reads of the buffer being overwritten
                __builtin_amdgcn_wave_barrier();
                __builtin_amdgcn_s_waitcnt(0xC07F);   // lgkmcnt(0)
                DMA_CHUNK(cc);
                __builtin_amdgcn_wave_barrier();
            }
        }

        const float f0 = emrd(tb + 8),  f1 = emrd(tb + 9);
        const float f2 = emrd(tb + 10), f3 = emrd(tb + 11);
        const float f4 = emrd(tb + 12), f5 = emrd(tb + 13);
        const float f6 = emrd(tb + 14), f7 = emrd(tb + 15);

        STEP(tb + 0, e0); STEP(tb + 1, e1); STEP(tb + 2, e2); STEP(tb + 3, e3);
        STEP(tb + 4, e4); STEP(tb + 5, e5); STEP(tb + 6, e6); STEP(tb + 7, e7);

        bpq[sb * 16] = acc;     // 64 consecutive dwords/wave: coalesced
        acc = 0u;

        e0 = f0; e1 = f1; e2 = f2; e3 = f3;
        e4 = f4; e5 = f5; e6 = f6; e7 = f7;
    }

    // tail: t = 505..511 (blk 63 holds subs 0..6)
    STEP(505, e0); STEP(506, e1); STEP(507, e2); STEP(508, e3);
    STEP(509, e4); STEP(510, e5); STEP(511, e6);
    bpq[63 * 16] = acc;

#undef STEP
#undef DMA_CHUNK

    // final 12-way max + first-index argmax (all lanes compute same result)
    float best;
    int last;
    {
        const float p0 = bcast16<0>(nv),  p1 = bcast16<1>(nv);
        const float p2 = bcast16<2>(nv),  p3 = bcast16<3>(nv);
        const float p4 = bcast16<4>(nv),  p5 = bcast16<5>(nv);
        const float p6 = bcast16<6>(nv),  p7 = bcast16<7>(nv);
        const float p8 = bcast16<8>(nv),  p9 = bcast16<9>(nv);
        const float p10 = bcast16<10>(nv), p11 = bcast16<11>(nv);
        const float mA = fmaxf(fmaxf(p0, p1), p2);
        const float mB = fmaxf(fmaxf(p3, p4), p5);
        const float mC = fmaxf(fmaxf(p6, p7), p8);
        const float mD = fmaxf(fmaxf(p9, p10), p11);
        best = fmaxf(fmaxf(mA, mB), fmaxf(mC, mD));
        int gA = (p1 == mA) ? 1 : 2;    gA = (p0 == mA) ? 0 : gA;
        int gB = (p4 == mB) ? 4 : 5;    gB = (p3 == mB) ? 3 : gB;
        int gC = (p7 == mC) ? 7 : 8;    gC = (p6 == mC) ? 6 : gC;
        int gD = (p10 == mD) ? 10 : 11; gD = (p9 == mD) ? 9 : gD;
        int bi = gD;
        bi = (mC == best) ? gC : bi;
        bi = (mB == best) ? gB : bi;
        bi = (mA == best) ? gA : bi;
        last = bi;
    }

    __syncthreads();   // drain bp stores before same-wave cross-lane readback

    // Backtrack: one lane per row. Per 8-step block: 12 dwords (3x dwordx4,
    // software-pipelined, address-independent) + in-register 12:1 mux by tag.
#define BTS(SUB, PB) do {                                                     \
    const uint32_t e0_ = (tag & 1) ? qa.y : qa.x;                             \
    const uint32_t e1_ = (tag & 1) ? qa.w : qa.z;                             \
    const uint32_t e2_ = (tag & 1) ? qb.y : qb.x;                             \
    const uint32_t e3_ = (tag & 1) ? qb.w : qb.z;                             \
    const uint32_t e4_ = (tag & 1) ? qc.y : qc.x;                             \
    const uint32_t e5_ = (tag & 1) ? qc.w : qc.z;                             \
    const uint32_t f0_ = (tag & 2) ? e1_ : e0_;                               \
    const uint32_t f1_ = (tag & 2) ? e3_ : e2_;                               \
    const uint32_t f2_ = (tag & 2) ? e5_ : e4_;                               \
    const uint32_t g0_ = (tag & 4) ? f1_ : f0_;                               \
    const uint32_t dw_ = (tag >= 8) ? f2_ : g0_;                              \
    tag = (int)((dw_ >> (4 * (SUB))) & 0xFu);                                 \
    paths[(PB) + (SUB)] = (float)tag;                                         \
} while (0)

    if (jl == 0) {
        out[b] = best;
        float* __restrict__ paths = out + kB + (size_t)b * kT;
        paths[kT - 1] = (float)last;

        int tag = last;
        const uint4* __restrict__ rec = (const uint4*)(bp + (size_t)b * 1024);

        uint4 qa = rec[63 * 4 + 0], qb = rec[63 * 4 + 1], qc = rec[63 * 4 + 2];
        uint4 na = rec[62 * 4 + 0], nb = rec[62 * 4 + 1], nc = rec[62 * 4 + 2];

        // blk 63: subs 6..0 (s = 510..504)
        BTS(6, 504); BTS(5, 504); BTS(4, 504); BTS(3, 504);
        BTS(2, 504); BTS(1, 504); BTS(0, 504);

#pragma unroll 1
        for (int blk = 62; blk >= 0; --blk) {
            qa = na; qb = nb; qc = nc;
            if (blk > 0) {
                na = rec[blk * 4 - 4];
                nb = rec[blk * 4 - 3];
                nc = rec[blk * 4 - 2];
            }
            const int pb = blk * 8;
            BTS(7, pb); BTS(6, pb); BTS(5, pb); BTS(4, pb);
            BTS(3, pb); BTS(2, pb); BTS(1, pb); BTS(0, pb);
        }
    }
#undef BTS
}

} // namespace

extern "C" void kernel_launch(void* const* d_in, const int* in_sizes, int n_in,
                              void* d_out, int out_size, void* d_ws, size_t ws_size,
                              hipStream_t stream) {
    const float* logits = (const float*)d_in[0];   // [8192, 512, 12] f32
    const float* trans  = (const float*)d_in[1];   // [12, 12] f32
    float* out = (float*)d_out;
    uint32_t* bp = (uint32_t*)d_ws;                // 8192*64*16*4 = 33.55 MB

    const int threads = 64;                        // 1 wave, 4 rows
    const int blocks = kB / kRows;                 // 2048 blocks -> 2 waves/SIMD
    viterbi_fused<<<blocks, threads, 0, stream>>>(logits, trans, out, bp);
}

// Round 3
// 445.462 us; speedup vs baseline: 1.1136x; 1.1035x over previous
//
#include <hip/hip_runtime.h>
#include <stdint.h>

// Batched Viterbi decode: B=8192, T=512, K=12.
// ZERO-LDS variant, r1-proven exchange. 16 lanes per batch row (lane jl owns
// state jl; lanes 12..15 spare), 4 rows per 64-lane wave, 2048 blocks
// (2 waves/SIMD on all 1024 SIMDs).
// Exchange: 12 ds_swizzle group-broadcasts (HW-verified correct in r1).
// Emissions: DIRECT global->register loads with an 8-step register lookahead
// (no __shared__, no DMA, no waitcnt schedule, no barriers in the hot loop) --
// this isolates the LDS-staging machinery that was common to r0/r1 (both
// 310 us with all pipes <40%).
// Backpointers: nibble-packed dword per 8 steps per state lane, tag j's trail
// at dword j of each 16-dword block; backtrack identical to r1 (proven).

namespace {

constexpr int kB = 8192;
constexpr int kT = 512;
constexpr int kK = 12;
constexpr int kRows = 4;     // batch rows per wave

template <int I>
__device__ __forceinline__ float bcast16(float x) {
    // ds_swizzle BitMode: src_lane = ((l & 0x10) | I) within each 32-lane
    // half => broadcast lane I of each 16-lane group to the whole group.
    // offset = (xor<<10) | (or<<5) | and = (I<<5) | 0x10.  [verified in r1]
    return __int_as_float(__builtin_amdgcn_ds_swizzle(
        __float_as_int(x), (I << 5) | 0x10));
}

__global__ __launch_bounds__(64, 2) void viterbi_fused(
    const float* __restrict__ logits,   // [B, T, K]
    const float* __restrict__ trans,    // [K, K]
    float* __restrict__ out,            // [B] scores + [B*T] paths (floats)
    uint32_t* __restrict__ bp)          // [B][64][16] dwords, 8 nibbles each
{
    const int ln    = threadIdx.x;      // 0..63
    const int grp   = ln >> 4;          // row within wave: 0..3
    const int jl    = ln & 15;          // state lane: 0..11 live, 12..15 spare
    const int j     = (jl < 12) ? jl : 11;   // clamp for loads
    const int brow0 = blockIdx.x * kRows;
    const int b     = brow0 + grp;

    // transition column j: T[i] = trans[i][j] (spare lanes duplicate col 11;
    // their results are never read: swizzles only source lanes 0..11)
    const float T0 = trans[0 * kK + j],  T1 = trans[1 * kK + j];
    const float T2 = trans[2 * kK + j],  T3 = trans[3 * kK + j];
    const float T4 = trans[4 * kK + j],  T5 = trans[5 * kK + j];
    const float T6 = trans[6 * kK + j],  T7 = trans[7 * kK + j];
    const float T8 = trans[8 * kK + j],  T9 = trans[9 * kK + j];
    const float T10 = trans[10 * kK + j], T11 = trans[11 * kK + j];

    uint32_t* __restrict__ bpq = bp + (size_t)b * 1024 + jl;

    // per-lane emission pointer: em[b][t][j]
    const float* __restrict__ gem = logits + (size_t)b * (kT * kK) + j;

    auto ld = [&](int t) -> float {
        const int tc = (t < kT) ? t : (kT - 1);
        return gem[tc * kK];
    };

    // trellis t=0
    float nv = ld(0);
    uint32_t acc = 0u;

    // 8-step emission lookahead in registers
    float e0 = ld(1), e1 = ld(2), e2 = ld(3), e3 = ld(4);
    float e4 = ld(5), e5 = ld(6), e6 = ld(7), e7 = ld(8);

    // One Viterbi step: 12 group-broadcasts, 12 adds, max3 tree, descending
    // first-index argmax chain (r1-proven), nibble pack.
#define STEP(TSTEP, EV_) do {                                                 \
    const float p0 = bcast16<0>(nv),  p1 = bcast16<1>(nv);                    \
    const float p2 = bcast16<2>(nv),  p3 = bcast16<3>(nv);                    \
    const float p4 = bcast16<4>(nv),  p5 = bcast16<5>(nv);                    \
    const float p6 = bcast16<6>(nv),  p7 = bcast16<7>(nv);                    \
    const float p8 = bcast16<8>(nv),  p9 = bcast16<9>(nv);                    \
    const float p10 = bcast16<10>(nv), p11 = bcast16<11>(nv);                 \
    const float x0 = p0 + T0,  x1 = p1 + T1,  x2 = p2 + T2;                   \
    const float x3 = p3 + T3,  x4 = p4 + T4,  x5 = p5 + T5;                   \
    const float x6 = p6 + T6,  x7 = p7 + T7,  x8 = p8 + T8;                   \
    const float x9 = p9 + T9,  x10 = p10 + T10, x11 = p11 + T11;              \
    const float mA = fmaxf(fmaxf(x0, x1), x2);                                \
    const float mB = fmaxf(fmaxf(x3, x4), x5);                                \
    const float mC = fmaxf(fmaxf(x6, x7), x8);                                \
    const float mD = fmaxf(fmaxf(x9, x10), x11);                              \
    const float best = fmaxf(fmaxf(mA, mB), fmaxf(mC, mD));                   \
    int bi = 11;                                                              \
    bi = (x10 == best) ? 10 : bi;  bi = (x9 == best) ? 9 : bi;                \
    bi = (x8  == best) ?  8 : bi;  bi = (x7 == best) ? 7 : bi;                \
    bi = (x6  == best) ?  6 : bi;  bi = (x5 == best) ? 5 : bi;                \
    bi = (x4  == best) ?  4 : bi;  bi = (x3 == best) ? 3 : bi;                \
    bi = (x2  == best) ?  2 : bi;  bi = (x1 == best) ? 1 : bi;                \
    bi = (x0  == best) ?  0 : bi;                                             \
    nv = best + (EV_);                                                        \
    acc |= (uint32_t)bi << (4 * (((TSTEP) - 1) & 7));                         \
} while (0)

    // main: t = 1..504 in 63 sub-blocks of 8
#pragma unroll 1
    for (int sb = 0; sb < 63; ++sb) {
        const int tb = 8 * sb + 1;

        const float f0 = ld(tb + 8),  f1 = ld(tb + 9);
        const float f2 = ld(tb + 10), f3 = ld(tb + 11);
        const float f4 = ld(tb + 12), f5 = ld(tb + 13);
        const float f6 = ld(tb + 14), f7 = ld(tb + 15);

        STEP(tb + 0, e0); STEP(tb + 1, e1); STEP(tb + 2, e2); STEP(tb + 3, e3);
        STEP(tb + 4, e4); STEP(tb + 5, e5); STEP(tb + 6, e6); STEP(tb + 7, e7);

        bpq[sb * 16] = acc;     // 16 dwords per (row,block): coalesced
        acc = 0u;

        e0 = f0; e1 = f1; e2 = f2; e3 = f3;
        e4 = f4; e5 = f5; e6 = f6; e7 = f7;
    }

    // tail: t = 505..511
    STEP(505, e0); STEP(506, e1); STEP(507, e2); STEP(508, e3);
    STEP(509, e4); STEP(510, e5); STEP(511, e6);
    bpq[63 * 16] = acc;

#undef STEP

    // final 12-way max + first-index argmax (all lanes compute same result)
    float best;
    int last;
    {
        const float p0 = bcast16<0>(nv),  p1 = bcast16<1>(nv);
        const float p2 = bcast16<2>(nv),  p3 = bcast16<3>(nv);
        const float p4 = bcast16<4>(nv),  p5 = bcast16<5>(nv);
        const float p6 = bcast16<6>(nv),  p7 = bcast16<7>(nv);
        const float p8 = bcast16<8>(nv),  p9 = bcast16<9>(nv);
        const float p10 = bcast16<10>(nv), p11 = bcast16<11>(nv);
        const float mA = fmaxf(fmaxf(p0, p1), p2);
        const float mB = fmaxf(fmaxf(p3, p4), p5);
        const float mC = fmaxf(fmaxf(p6, p7), p8);
        const float mD = fmaxf(fmaxf(p9, p10), p11);
        best = fmaxf(fmaxf(mA, mB), fmaxf(mC, mD));
        int bi = 11;
        bi = (p10 == best) ? 10 : bi;  bi = (p9 == best) ? 9 : bi;
        bi = (p8  == best) ?  8 : bi;  bi = (p7 == best) ? 7 : bi;
        bi = (p6  == best) ?  6 : bi;  bi = (p5 == best) ? 5 : bi;
        bi = (p4  == best) ?  4 : bi;  bi = (p3 == best) ? 3 : bi;
        bi = (p2  == best) ?  2 : bi;  bi = (p1 == best) ? 1 : bi;
        bi = (p0  == best) ?  0 : bi;
        last = bi;
    }

    __syncthreads();   // drain bp stores before same-wave cross-lane readback

    // Backtrack: one lane per row. Per 8-step block: 12 dwords (3x dwordx4,
    // software-pipelined, address-independent) + in-register 12:1 mux by tag.
#define BTS(SUB, PB) do {                                                     \
    const uint32_t e0_ = (tag & 1) ? qa.y : qa.x;                             \
    const uint32_t e1_ = (tag & 1) ? qa.w : qa.z;                             \
    const uint32_t e2_ = (tag & 1) ? qb.y : qb.x;                             \
    const uint32_t e3_ = (tag & 1) ? qb.w : qb.z;                             \
    const uint32_t e4_ = (tag & 1) ? qc.y : qc.x;                             \
    const uint32_t e5_ = (tag & 1) ? qc.w : qc.z;                             \
    const uint32_t f0_ = (tag & 2) ? e1_ : e0_;                               \
    const uint32_t f1_ = (tag & 2) ? e3_ : e2_;                               \
    const uint32_t f2_ = (tag & 2) ? e5_ : e4_;                               \
    const uint32_t g0_ = (tag & 4) ? f1_ : f0_;                               \
    const uint32_t dw_ = (tag >= 8) ? f2_ : g0_;                              \
    tag = (int)((dw_ >> (4 * (SUB))) & 0xFu);                                 \
    paths[(PB) + (SUB)] = (float)tag;                                         \
} while (0)

    if (jl == 0) {
        out[b] = best;
        float* __restrict__ paths = out + kB + (size_t)b * kT;
        paths[kT - 1] = (float)last;

        int tag = last;
        const uint4* __restrict__ rec = (const uint4*)(bp + (size_t)b * 1024);

        uint4 qa = rec[63 * 4 + 0], qb = rec[63 * 4 + 1], qc = rec[63 * 4 + 2];
        uint4 na = rec[62 * 4 + 0], nb = rec[62 * 4 + 1], nc = rec[62 * 4 + 2];

        // blk 63: subs 6..0 (s = 510..504)
        BTS(6, 504); BTS(5, 504); BTS(4, 504); BTS(3, 504);
        BTS(2, 504); BTS(1, 504); BTS(0, 504);

#pragma unroll 1
        for (int blk = 62; blk >= 0; --blk) {
            qa = na; qb = nb; qc = nc;
            if (blk > 0) {
                na = rec[blk * 4 - 4];
                nb = rec[blk * 4 - 3];
                nc = rec[blk * 4 - 2];
            }
            const int pb = blk * 8;
            BTS(7, pb); BTS(6, pb); BTS(5, pb); BTS(4, pb);
            BTS(3, pb); BTS(2, pb); BTS(1, pb); BTS(0, pb);
        }
    }
#undef BTS
}

} // namespace

extern "C" void kernel_launch(void* const* d_in, const int* in_sizes, int n_in,
                              void* d_out, int out_size, void* d_ws, size_t ws_size,
                              hipStream_t stream) {
    const float* logits = (const float*)d_in[0];   // [8192, 512, 12] f32
    const float* trans  = (const float*)d_in[1];   // [12, 12] f32
    float* out = (float*)d_out;
    uint32_t* bp = (uint32_t*)d_ws;                // 8192*64*16*4 = 33.55 MB

    const int threads = 64;                        // 1 wave, 4 rows
    const int blocks = kB / kRows;                 // 2048 blocks -> 2 waves/SIMD
    viterbi_fused<<<blocks, threads, 0, stream>>>(logits, trans, out, bp);
}

// Round 4
// 429.702 us; speedup vs baseline: 1.1544x; 1.0367x over previous
//
#include <hip/hip_runtime.h>
#include <stdint.h>

// Batched Viterbi decode: B=8192, T=512, K=12.
// r4 = r0's HW-verified quad_perm exchange + r3's HW-verified zero-LDS
// direct-global emissions. Geometry: 4 lanes per batch row (3 tag-columns
// per lane, j0 = 3*c), 16 rows per 64-lane wave, 512 blocks (2 waves/CU,
// each wave saturating its own SIMD's issue).
// Rationale (r3 counters): 12 ds_swizzle/step x 8 waves/CU serialized on the
// CU's single LDS pipe (~1200 cyc/step measured ~= 96 ops x ~12 cyc). The
// quad_perm exchange is pure VALU (4 pipes/CU) and each wave carries 16 rows,
// cutting per-row issue cost; zero LDS ops remain anywhere in the kernel.
// Emissions: direct global->register vf3 loads, 8-step lookahead (no DMA,
// no waitcnt schedule, no barriers in the hot loop).
// Backpointers: r0's proven 3-nibbles-in-ushort per (row,step,lane) layout
// and its proven backtrack mux.

namespace {

constexpr int kB = 8192;
constexpr int kT = 512;
constexpr int kK = 12;

typedef float vf3 __attribute__((ext_vector_type(3)));

template <int CTRL>
__device__ __forceinline__ float dppb(float x) {
    // quad_perm broadcast of quad-lane q: CTRL = q * 0x55  [HW-verified r0]
    return __int_as_float(__builtin_amdgcn_update_dpp(
        0, __float_as_int(x), CTRL, 0xf, 0xf, true));
}

__global__ __launch_bounds__(64) void viterbi_fused(
    const float* __restrict__ logits,   // [B, T, K]
    const float* __restrict__ trans,    // [K, K]
    float* __restrict__ out,            // [B] scores + [B*T] paths (floats)
    uint16_t* __restrict__ bp)          // [B][511][4] ushorts (3 nibbles each)
{
    const int ln = threadIdx.x;     // 0..63
    const int qd = ln >> 2;         // row within wave: 0..15
    const int c  = ln & 3;          // quad lane = column group
    const int b  = blockIdx.x * 16 + qd;
    const int j0 = 3 * c;           // this lane's columns j0..j0+2

    // transition columns j0, j0+1, j0+2 (36 regs)
    float TA[12], TB[12], TC[12];
#pragma unroll
    for (int i = 0; i < 12; ++i) {
        TA[i] = trans[i * kK + j0];
        TB[i] = trans[i * kK + j0 + 1];
        TC[i] = trans[i * kK + j0 + 2];
    }

    uint16_t* __restrict__ bps = bp + (size_t)b * 511 * 4 + c;

    // per-lane emission pointer: em[b][t][j0..j0+2]
    const float* __restrict__ gem = logits + (size_t)b * (kT * kK) + j0;

    // direct global load of this lane's 3 emission floats at step t
    auto ld = [&](int t) -> vf3 {
        const int tc = (t < kT) ? t : (kT - 1);
        vf3 v;
        __builtin_memcpy(&v, gem + (size_t)tc * kK, 12);   // dwordx3, 4B-align
        return v;
    };

    // trellis t=0 in n0..n2 (this lane's 3 columns)
    vf3 iv = ld(0);
    float n0 = iv.x, n1 = iv.y, n2 = iv.z;

    // 8-step emission lookahead in registers
    vf3 e0 = ld(1), e1 = ld(2), e2 = ld(3), e3 = ld(4);
    vf3 e4 = ld(5), e5 = ld(6), e6 = ld(7), e7 = ld(8);

    // prev[3q+r] = quad-lane q's n_r   [HW-verified r0]
#define GATHER()                                                             \
    const float p0 = dppb<0x00>(n0), p1 = dppb<0x00>(n1), p2 = dppb<0x00>(n2);\
    const float p3 = dppb<0x55>(n0), p4 = dppb<0x55>(n1), p5 = dppb<0x55>(n2);\
    const float p6 = dppb<0xAA>(n0), p7 = dppb<0xAA>(n1), p8 = dppb<0xAA>(n2);\
    const float p9 = dppb<0xFF>(n0), p10 = dppb<0xFF>(n1), p11 = dppb<0xFF>(n2)

    // one output column: 12 adds, max tree, descending first-index argmax
#define COLX(Tc, EMITc, NOUT, BIOUT) do {                                    \
    const float x0 = p0 + Tc[0],  x1 = p1 + Tc[1],  x2 = p2 + Tc[2];         \
    const float x3 = p3 + Tc[3],  x4 = p4 + Tc[4],  x5 = p5 + Tc[5];         \
    const float x6 = p6 + Tc[6],  x7 = p7 + Tc[7],  x8 = p8 + Tc[8];         \
    const float x9 = p9 + Tc[9],  x10 = p10 + Tc[10], x11 = p11 + Tc[11];    \
    const float mA = fmaxf(fmaxf(x0, x1), x2);                               \
    const float mB = fmaxf(fmaxf(x3, x4), x5);                               \
    const float mC = fmaxf(fmaxf(x6, x7), x8);                               \
    const float mD = fmaxf(fmaxf(x9, x10), x11);                             \
    const float best = fmaxf(fmaxf(mA, mB), fmaxf(mC, mD));                  \
    int bi = 11;                                                             \
    bi = (x10 == best) ? 10 : bi;  bi = (x9 == best) ? 9 : bi;               \
    bi = (x8  == best) ?  8 : bi;  bi = (x7 == best) ? 7 : bi;               \
    bi = (x6  == best) ?  6 : bi;  bi = (x5 == best) ? 5 : bi;               \
    bi = (x4  == best) ?  4 : bi;  bi = (x3 == best) ? 3 : bi;               \
    bi = (x2  == best) ?  2 : bi;  bi = (x1 == best) ? 1 : bi;               \
    bi = (x0  == best) ?  0 : bi;                                            \
    NOUT = best + (EMITc);  BIOUT = bi;                                      \
} while (0)

#define STEP(TT, EV) do {                                                    \
    GATHER();                                                                \
    float q0_, q1_, q2_; int b0_, b1_, b2_;                                  \
    COLX(TA, (EV).x, q0_, b0_);                                              \
    COLX(TB, (EV).y, q1_, b1_);                                              \
    COLX(TC, (EV).z, q2_, b2_);                                              \
    n0 = q0_; n1 = q1_; n2 = q2_;                                            \
    const uint32_t w_ = (uint32_t)b0_ | ((uint32_t)b1_ << 4)                 \
                        | ((uint32_t)b2_ << 8);                              \
    bps[(size_t)((TT) - 1) * 4] = (uint16_t)w_;                              \
} while (0)

    // main: t = 1..504 in 63 sub-blocks of 8 (r3-proven cadence, no waits)
#pragma unroll 1
    for (int sb = 0; sb < 63; ++sb) {
        const int tb = 8 * sb + 1;

        const vf3 f0 = ld(tb + 8),  f1 = ld(tb + 9);
        const vf3 f2 = ld(tb + 10), f3 = ld(tb + 11);
        const vf3 f4 = ld(tb + 12), f5 = ld(tb + 13);
        const vf3 f6 = ld(tb + 14), f7 = ld(tb + 15);

        STEP(tb + 0, e0); STEP(tb + 1, e1); STEP(tb + 2, e2); STEP(tb + 3, e3);
        STEP(tb + 4, e4); STEP(tb + 5, e5); STEP(tb + 6, e6); STEP(tb + 7, e7);

        e0 = f0; e1 = f1; e2 = f2; e3 = f3;
        e4 = f4; e5 = f5; e6 = f6; e7 = f7;
    }

    // tail: t = 505..511 (e0..e6 hold em[505..511])
    STEP(505, e0); STEP(506, e1); STEP(507, e2); STEP(508, e3);
    STEP(509, e4); STEP(510, e5); STEP(511, e6);

#undef STEP

    // final 12-way max + first-index argmax (all 4 quad lanes agree)
    float best;
    int last;
    {
        GATHER();
        const float mA = fmaxf(fmaxf(p0, p1), p2);
        const float mB = fmaxf(fmaxf(p3, p4), p5);
        const float mC = fmaxf(fmaxf(p6, p7), p8);
        const float mD = fmaxf(fmaxf(p9, p10), p11);
        best = fmaxf(fmaxf(mA, mB), fmaxf(mC, mD));
        int bi = 11;
        bi = (p10 == best) ? 10 : bi;  bi = (p9 == best) ? 9 : bi;
        bi = (p8  == best) ?  8 : bi;  bi = (p7 == best) ? 7 : bi;
        bi = (p6  == best) ?  6 : bi;  bi = (p5 == best) ? 5 : bi;
        bi = (p4  == best) ?  4 : bi;  bi = (p3 == best) ? 3 : bi;
        bi = (p2  == best) ?  2 : bi;  bi = (p1 == best) ? 1 : bi;
        bi = (p0  == best) ?  0 : bi;
        last = bi;
    }
#undef GATHER
#undef COLX

    __syncthreads();   // drain backpointer stores before same-wave readback

    // Backtrack (r0-proven): one lane per row reads its ushort records and
    // follows the chain with an in-register nibble mux.
    if (c == 0) {
        out[b] = best;
        float* __restrict__ paths = out + kB + (size_t)b * kT;
        paths[kT - 1] = (float)last;

        int tag = last;
        const uint2* __restrict__ rec = (const uint2*)(bp + (size_t)b * 511 * 4);
#pragma unroll 4
        for (int s = 510; s >= 0; --s) {
            const uint2 q = rec[s];
            const int d3 = (tag * 11) >> 5;        // tag / 3  (exact for 0..15)
            const int rm = tag - 3 * d3;           // tag % 3
            const uint32_t dw = (d3 & 2) ? q.y : q.x;
            const int sh = ((d3 & 1) << 4) + (rm << 2);
            tag = (int)((dw >> sh) & 0xF);
            paths[s] = (float)tag;
        }
    }
}

} // namespace

extern "C" void kernel_launch(void* const* d_in, const int* in_sizes, int n_in,
                              void* d_out, int out_size, void* d_ws, size_t ws_size,
                              hipStream_t stream) {
    const float* logits = (const float*)d_in[0];   // [8192, 512, 12] f32
    const float* trans  = (const float*)d_in[1];   // [12, 12] f32
    float* out = (float*)d_out;
    uint16_t* bp = (uint16_t*)d_ws;                // 8192*511*4*2 = 33.5 MB

    const int threads = 64;                        // 1 wave, 16 rows
    const int blocks = kB / 16;                    // 512 blocks
    viterbi_fused<<<blocks, threads, 0, stream>>>(logits, trans, out, bp);
}